// Round 16
// baseline (58.943 us; speedup 1.0000x reference)
//
#include <hip/hip_runtime.h>
#include <hip/hip_bf16.h>

constexpr int HID = 1024;
constexpr int KD  = 16;    // probe directions
constexpr int TM  = 16;    // rows per tile
constexpr int NW  = 8;     // waves per block
constexpr int TPB = 4;     // tiles per block -> 512 blocks = 2 blocks/CU
constexpr int NH  = 2*TPB; // half-tiles per block

typedef short bf16x8 __attribute__((ext_vector_type(8)));   // MFMA A/B frag
typedef float f32x4  __attribute__((ext_vector_type(4)));   // MFMA C/D frag

__device__ __forceinline__ short f2b(float x) {
    __hip_bfloat16 b = __float2bfloat16(x);
    return *reinterpret_cast<short*>(&b);
}
__device__ __forceinline__ float b2f(short s) {
    return __uint_as_float(((unsigned int)(unsigned short)s) << 16);
}

// Wave w owns global cols {w*64..w*64+63} U {512+w*64..512+w*64+63}.
// chunk p=0..3: gb(w,p) = (p<2) ? w*64+p*32 : 512+w*64+(p-2)*32.
// Qt[r][k] = bf16(Q[k][r]) (16x1024): coef B-frags, 16B contiguous reads.
// Qa permuted (64x16x16): epilogue A-frags s.t. epilogue MFMA's D-layout
// lands exactly on the coef A-frag register layout (R13 scheme, new gb).
__global__ void q_setup(const float* __restrict__ Qf,
                        short* __restrict__ Qt, short* __restrict__ Qa) {
    const int idx = blockIdx.x*256 + threadIdx.x;
    if (idx < 16*HID) {
        const int r = idx >> 10, k = idx & 1023;
        Qt[idx] = f2b(Qf[k*KD + r]);
        const int gs = idx >> 4, dir = idx & 15;
        const int jslot = gs >> 4, rr = gs & 15;
        const int w = jslot >> 3, jl = jslot & 7;
        const int p = jl >> 1, odd = jl & 1;
        const int gb = (p < 2) ? w*64 + p*32 : 512 + w*64 + (p-2)*32;
        const int col = gb + (rr >> 2)*8 + odd*4 + (rr & 3);
        Qa[idx] = f2b(Qf[col*KD + dir]);
    }
}

#define SCHED_FENCE() __builtin_amdgcn_sched_barrier(0)

// Stage one 32KB half-tile (16 rows x 512 cols) via global_load_lds.
// Wave w stages rows 2w, 2w+1 (4 instructions). 16B-piece swizzle ^(row&7)
// applied on the GLOBAL source (LDS dest linear); reads apply the same XOR.
__device__ __forceinline__ void stage_half(float* ldsBuf, const float* Hbase,
                                           int half, int w, int lane) {
    #pragma unroll
    for (int i = 0; i < 4; ++i) {
        const int rr = w*2 + (i >> 1);
        const int s0 = (i & 1)*64;
        const int s  = s0 + lane;                    // 16B piece in [0,128)
        const float* g = Hbase + rr*1024 + half*512 + ((s ^ (rr & 7)) << 2);
        const float* l = ldsBuf + rr*512 + s0*4;     // wave-uniform; HW adds lane*16
        __builtin_amdgcn_global_load_lds(
            (const __attribute__((address_space(1))) void*)g,
            (__attribute__((address_space(3))) void*)l, 16, 0, 0);
    }
}

__global__ __launch_bounds__(NW*64)
void probe_removal_hh(const float* __restrict__ H,
                      const short* __restrict__ Qt,
                      const short* __restrict__ Qa,
                      float* __restrict__ out)
{
    const int lane = threadIdx.x & 63;
    const int w    = threadIdx.x >> 6;
    const int r    = lane & 15;
    const int q    = lane >> 4;

    __shared__ __align__(16) float Hb[2][TM][512];   // 64 KB half-tile dbuf
    __shared__ __align__(16) float ctr[NW][TM][20];  // coef partials
    __shared__ float s2p[NW][TM];

    const int tile0 = blockIdx.x * TPB;
    const float* Hblk = H + (size_t)tile0*TM*HID;

    // ---- persistent Q fragments ----
    bf16x8 bq[4];
    #pragma unroll
    for (int kt = 0; kt < 4; ++kt) {
        const int gb = (kt < 2) ? w*64 + kt*32 : 512 + w*64 + (kt-2)*32;
        bq[kt] = *reinterpret_cast<const bf16x8*>(Qt + r*1024 + gb + q*8);
    }
    bf16x8 aq0[4], aq1[4];
    #pragma unroll
    for (int p = 0; p < 4; ++p) {
        if (q < 2) {
            aq0[p] = *reinterpret_cast<const bf16x8*>(Qa + ((w*8 + 2*p    )*16 + r)*KD + q*8);
            aq1[p] = *reinterpret_cast<const bf16x8*>(Qa + ((w*8 + 2*p + 1)*16 + r)*KD + q*8);
        } else {
            #pragma unroll
            for (int i = 0; i < 8; ++i) { aq0[p][i] = 0; aq1[p][i] = 0; }
        }
    }
    SCHED_FENCE();

    // ---- prologue: stage halves 0 (buf0) and 1 (buf1) ----
    stage_half(&Hb[0][0][0], Hblk, 0, w, lane);
    SCHED_FENCE();
    stage_half(&Hb[1][0][0], Hblk + 0*TM*HID + 0, 1, w, lane);   // half 1 of tile 0
    SCHED_FENCE();
    asm volatile("s_waitcnt vmcnt(4)" ::: "memory");   // half 0 landed
    SCHED_FENCE();
    __builtin_amdgcn_s_barrier();

    #pragma unroll
    for (int t = 0; t < TPB; ++t) {
        const float* Htile = Hblk + (size_t)t*TM*HID;
        bf16x8 af[4];
        f32x4 acc0 = {0.f,0.f,0.f,0.f}, acc1 = {0.f,0.f,0.f,0.f};
        float s2 = 0.f;

        // ---- coef on half a (buf0): chunks kt=0,1 ----
        #pragma unroll
        for (int c = 0; c < 2; ++c) {
            const int ploc = w*16 + c*8 + q*2;
            const int sx = ploc ^ (r & 7);
            const char* B = (const char*)&Hb[0][0][0];
            const float4 x = *(const float4*)(B + r*2048 + sx*16);
            const float4 y = *(const float4*)(B + r*2048 + (sx^1)*16);
            s2 = fmaf(x.x,x.x, fmaf(x.y,x.y, fmaf(x.z,x.z, fmaf(x.w,x.w, s2))));
            s2 = fmaf(y.x,y.x, fmaf(y.y,y.y, fmaf(y.z,y.z, fmaf(y.w,y.w, s2))));
            bf16x8 a;
            a[0]=f2b(x.x); a[1]=f2b(x.y); a[2]=f2b(x.z); a[3]=f2b(x.w);
            a[4]=f2b(y.x); a[5]=f2b(y.y); a[6]=f2b(y.z); a[7]=f2b(y.w);
            af[c] = a;
            if (c) acc1 = __builtin_amdgcn_mfma_f32_16x16x32_bf16(a, bq[1], acc1, 0, 0, 0);
            else   acc0 = __builtin_amdgcn_mfma_f32_16x16x32_bf16(a, bq[0], acc0, 0, 0, 0);
        }
        // wait: half 2t+1 landed (own stage loads), then publish buf0 free
        if (t == 0) { asm volatile("s_waitcnt vmcnt(0)" ::: "memory"); }
        else        { asm volatile("s_waitcnt vmcnt(8)" ::: "memory"); }
        SCHED_FENCE();
        __builtin_amdgcn_s_barrier();      // A: all waves done reading buf0
        SCHED_FENCE();
        if (2*t + 2 < NH)
            stage_half(&Hb[0][0][0], Hblk + (size_t)(t+1)*TM*HID, 0, w, lane);
        SCHED_FENCE();

        // ---- coef on half b (buf1): chunks kt=2,3 ----
        #pragma unroll
        for (int c = 0; c < 2; ++c) {
            const int ploc = w*16 + c*8 + q*2;
            const int sx = ploc ^ (r & 7);
            const char* B = (const char*)&Hb[1][0][0];
            const float4 x = *(const float4*)(B + r*2048 + sx*16);
            const float4 y = *(const float4*)(B + r*2048 + (sx^1)*16);
            s2 = fmaf(x.x,x.x, fmaf(x.y,x.y, fmaf(x.z,x.z, fmaf(x.w,x.w, s2))));
            s2 = fmaf(y.x,y.x, fmaf(y.y,y.y, fmaf(y.z,y.z, fmaf(y.w,y.w, s2))));
            bf16x8 a;
            a[0]=f2b(x.x); a[1]=f2b(x.y); a[2]=f2b(x.z); a[3]=f2b(x.w);
            a[4]=f2b(y.x); a[5]=f2b(y.y); a[6]=f2b(y.z); a[7]=f2b(y.w);
            af[2 + c] = a;
            if (c) acc1 = __builtin_amdgcn_mfma_f32_16x16x32_bf16(a, bq[3], acc1, 0, 0, 0);
            else   acc0 = __builtin_amdgcn_mfma_f32_16x16x32_bf16(a, bq[2], acc0, 0, 0, 0);
        }
        const f32x4 acc = acc0 + acc1;
        s2 += __shfl_xor(s2, 16);
        s2 += __shfl_xor(s2, 32);

        #pragma unroll
        for (int i = 0; i < 4; ++i) ctr[w][q*4 + i][r] = acc[i];
        if (q == 0) s2p[w][r] = s2;

        asm volatile("s_waitcnt lgkmcnt(0)" ::: "memory");
        SCHED_FENCE();
        __builtin_amdgcn_s_barrier();      // B: ctr ready; buf1 free
        SCHED_FENCE();
        if (2*t + 3 < NH)
            stage_half(&Hb[1][0][0], Hblk + (size_t)(t+1)*TM*HID, 1, w, lane);
        SCHED_FENCE();

        // ---- cross-wave reduce -> coefs, scale, pb ----
        float cf[8] = {0,0,0,0,0,0,0,0};
        if (q < 2) {
            #pragma unroll
            for (int w2 = 0; w2 < NW; ++w2) {
                const float4 a = *reinterpret_cast<const float4*>(&ctr[w2][r][q*8]);
                const float4 b = *reinterpret_cast<const float4*>(&ctr[w2][r][q*8 + 4]);
                cf[0]+=a.x; cf[1]+=a.y; cf[2]+=a.z; cf[3]+=a.w;
                cf[4]+=b.x; cf[5]+=b.y; cf[6]+=b.z; cf[7]+=b.w;
            }
        }
        float s2tot = 0.f;
        #pragma unroll
        for (int w2 = 0; w2 < NW; ++w2) s2tot += s2p[w2][r];

        float sc2 = 0.f;
        #pragma unroll
        for (int i = 0; i < 8; ++i) sc2 = fmaf(cf[i], cf[i], sc2);
        sc2 += __shfl_xor(sc2, 16);
        sc2 += __shfl_xor(sc2, 32);
        const float scale = rsqrtf(fmaxf(1.0f - sc2 / s2tot, 1e-20f));

        bf16x8 pb;
        #pragma unroll
        for (int i = 0; i < 8; ++i) pb[i] = f2b(cf[i]);

        // ---- fused epilogue: h from af registers; 8 stores per lane ----
        float* orow = out + (size_t)(tile0 + t)*TM*HID + r*HID;
        const f32x4 zero4 = {0.f,0.f,0.f,0.f};
        #pragma unroll
        for (int p = 0; p < 4; ++p) {
            const int gb = (p < 2) ? w*64 + p*32 : 512 + w*64 + (p-2)*32;
            const f32x4 d0 = __builtin_amdgcn_mfma_f32_16x16x32_bf16(aq0[p], pb, zero4, 0, 0, 0);
            const f32x4 d1 = __builtin_amdgcn_mfma_f32_16x16x32_bf16(aq1[p], pb, zero4, 0, 0, 0);
            f32x4 o0, o1;
            #pragma unroll
            for (int ii = 0; ii < 4; ++ii) {
                o0[ii] = (b2f(af[p][ii])     - d0[ii]) * scale;
                o1[ii] = (b2f(af[p][4 + ii]) - d1[ii]) * scale;
            }
            *reinterpret_cast<f32x4*>(orow + gb + q*8)     = o0;
            *reinterpret_cast<f32x4*>(orow + gb + q*8 + 4) = o1;
        }
        SCHED_FENCE();

        // ---- end-of-tile: wait stage(2t+2) landed (oldest 4 of 16);
        //      stage(2t+3) + this tile's stores stay in flight ----
        if (t < TPB-1) {
            asm volatile("s_waitcnt vmcnt(12)" ::: "memory");
            SCHED_FENCE();
            __builtin_amdgcn_s_barrier();  // C
            SCHED_FENCE();
        }
    }
}

extern "C" void kernel_launch(void* const* d_in, const int* in_sizes, int n_in,
                              void* d_out, int out_size, void* d_ws, size_t ws_size,
                              hipStream_t stream) {
    const float* H  = (const float*)d_in[0];   // [8,4096,1024] f32
    const float* Qf = (const float*)d_in[1];   // [1024,16] f32, orthonormal cols
    float* outp     = (float*)d_out;
    const int nrows  = in_sizes[0] / HID;      // 32768
    const int ntiles = nrows / TM;             // 2048

    short* Qt = (short*)d_ws;                  // 32 KB
    short* Qa = Qt + 16*HID;                   // 32 KB (permuted)

    hipLaunchKernelGGL(q_setup, dim3(64), dim3(256), 0, stream, Qf, Qt, Qa);

    // ~75KB LDS -> 2 blocks/CU; 512 blocks x 8 waves = 4 waves/SIMD with
    // two DECORRELATED blocks per CU (one streams while the other drains)
    hipLaunchKernelGGL(probe_removal_hh, dim3(ntiles / TPB), dim3(NW*64), 0, stream,
                       H, Qt, Qa, outp);
}